// Round 10
// baseline (264.426 us; speedup 1.0000x reference)
//
#include <hip/hip_runtime.h>
#include <hip/hip_bf16.h>

typedef __attribute__((ext_vector_type(8))) short short8;
typedef __attribute__((ext_vector_type(4))) short short4v;
typedef __attribute__((ext_vector_type(4))) float floatx4;
typedef __attribute__((ext_vector_type(2))) unsigned int uint2v;
typedef unsigned short u16;

#define B_SZ 4
#define NH   16
#define SEQ  2048
#define DM   1024
#define DK   64
#define M_ROWS (B_SZ * SEQ)   // 8192

__device__ __forceinline__ u16 f2bf(float f) {
  unsigned u = __float_as_uint(f);
  u += 0x7fff + ((u >> 16) & 1);   // RNE
  return (u16)(u >> 16);
}

// packed f32x2 -> bf16x2 (RNE), single instruction
__device__ __forceinline__ unsigned cvt_pk_bf16(float lo, float hi) {
  unsigned r;
  asm("v_cvt_pk_bf16_f32 %0, %1, %2" : "=v"(r) : "v"(lo), "v"(hi));
  return r;
}

// async global->LDS: dest = wave-uniform base + lane*16B (verified constraint)
__device__ __forceinline__ void async_copy16(const u16* g, const short* lds) {
  __builtin_amdgcn_global_load_lds(
      (const __attribute__((address_space(1))) void*)g,
      (__attribute__((address_space(3))) void*)lds,
      16, 0, 0);
}

#define BAR() do { __builtin_amdgcn_s_barrier(); asm volatile("" ::: "memory"); } while (0)

// ---------------------------------------------------------------------------
// cvt4: fp32->bf16 for x (y=0) and Wq/Wk/Wv (y=1..3). grid=(1024,4).
// ---------------------------------------------------------------------------
__global__ __launch_bounds__(256)
void cvt4_kernel(const float* __restrict__ x,
                 const float* __restrict__ wq, const float* __restrict__ wk,
                 const float* __restrict__ wv,
                 u16* __restrict__ xb, u16* __restrict__ wb)
{
  const int y = blockIdx.y;
  const float* src; u16* dst; int n4;
  if (y == 0)      { src = x;  dst = xb;                 n4 = (M_ROWS * DM) / 4; }
  else if (y == 1) { src = wq; dst = wb;                 n4 = (DM * DM) / 4; }
  else if (y == 2) { src = wk; dst = wb + DM * DM;       n4 = (DM * DM) / 4; }
  else             { src = wv; dst = wb + 2 * DM * DM;   n4 = (DM * DM) / 4; }
  for (int i = blockIdx.x * 256 + threadIdx.x; i < n4; i += gridDim.x * 256) {
    floatx4 v = ((const floatx4*)src)[i];
    short4v s;
#pragma unroll
    for (int e = 0; e < 4; ++e) s[e] = (short)f2bf(v[e]);
    ((short4v*)dst)[i] = s;
  }
}

__global__ __launch_bounds__(256)
void cvt1_kernel(const float* __restrict__ in, u16* __restrict__ out, int n4)
{
  for (int i = blockIdx.x * 256 + threadIdx.x; i < n4; i += gridDim.x * 256) {
    floatx4 v = ((const floatx4*)in)[i];
    short4v s;
#pragma unroll
    for (int e = 0; e < 4; ++e) s[e] = (short)f2bf(v[e]);
    ((short4v*)out)[i] = s;
  }
}

// ---------------------------------------------------------------------------
// GEMM core, 128x128 / BK=32 / 4 waves (unchanged from round 8 -- passed).
// ---------------------------------------------------------------------------
__device__ __forceinline__ void stage_tile128(
    const u16* __restrict__ Asrc, const u16* __restrict__ Bsrc,  // (row0, k0)
    short* sA, short* sB, int w, int lane)
{
  const int cu  = (lane & 3) ^ ((lane >> 2) & 3) ^ ((lane >> 4) & 3);
  const int rlo = lane >> 2;                      // 0..15
#pragma unroll
  for (int j = 0; j < 2; ++j) {
    const int oct = w * 2 + j;                    // 0..7 (16 rows each)
    const int row = oct * 16 + rlo;
    async_copy16(Asrc + (size_t)row * DM + cu * 8, sA + oct * 512);
  }
#pragma unroll
  for (int j = 0; j < 2; ++j) {
    const int oct = w * 2 + j;
    const int row = oct * 16 + rlo;
    async_copy16(Bsrc + (size_t)row * DM + cu * 8, sB + oct * 512);
  }
}

__device__ __forceinline__ void gemm128_core(
    const u16* __restrict__ A, const u16* __restrict__ B,
    int m0, int n0, floatx4 (&acc)[4][4])
{
  __shared__ short smem[16384];                   // 32 KiB: 2 x (A 4096 + B 4096)

  const int tid  = threadIdx.x;
  const int w    = tid >> 6;
  const int lane = tid & 63;
  const int wm   = w >> 1, wn = w & 1;            // wave grid 2(M) x 2(N)
  const int quad = lane >> 4, l16 = lane & 15;
  const int rswz = (l16 & 3) ^ ((l16 >> 2) & 3);

  short* sA_[2] = { smem,        smem + 8192 };
  short* sB_[2] = { smem + 4096, smem + 12288 };

#pragma unroll
  for (int mi = 0; mi < 4; ++mi)
#pragma unroll
    for (int ni = 0; ni < 4; ++ni)
      acc[mi][ni] = floatx4{0.f, 0.f, 0.f, 0.f};

  const u16* Abase = A + (size_t)m0 * DM;
  const u16* Bbase = B + (size_t)n0 * DM;

  // ---- prologue: stage tiles 0 (buf0) and 1 (buf1), 4 loads/wave each ----
  stage_tile128(Abase,      Bbase,      sA_[0], sB_[0], w, lane);
  stage_tile128(Abase + 32, Bbase + 32, sA_[1], sB_[1], w, lane);
  asm volatile("s_waitcnt vmcnt(4)" ::: "memory");   // tile0 landed
  BAR();

  short8 af[4], bf[4];

  for (int i = 0; i < 16; ++i) {                  // tiles 2i, 2i+1
    const bool nl = (i < 15);                     // stage tiles 2i+2 / 2i+3
#pragma unroll
    for (int half = 0; half < 2; ++half) {
      short* cA = sA_[half];
      short* cB = sB_[half];
      const int kof_n = (2 * i + 2 + half) * 32;  // staging k-offset (if nl)

      // ---- issue ALL 8 K-tile ds_reads (B-lo, A, B-hi) ----
#pragma unroll
      for (int nt = 0; nt < 2; ++nt)
        bf[nt] = *(const short8*)(cB + (wn * 64 + nt * 16 + l16) * 32
                                     + ((quad ^ rswz) << 3));
#pragma unroll
      for (int mi = 0; mi < 4; ++mi)
        af[mi] = *(const short8*)(cA + (wm * 64 + mi * 16 + l16) * 32
                                     + ((quad ^ rswz) << 3));
#pragma unroll
      for (int nt = 2; nt < 4; ++nt)
        bf[nt] = *(const short8*)(cB + (wn * 64 + nt * 16 + l16) * 32
                                     + ((quad ^ rswz) << 3));

      // ---- q1 (m-lo x n-lo), q2 (m-lo x n-hi), q3 (m-hi x n-hi) ----
      __builtin_amdgcn_s_setprio(1);
#pragma unroll
      for (int mi = 0; mi < 2; ++mi)
#pragma unroll
        for (int nt = 0; nt < 4; ++nt)
          acc[mi][nt] = __builtin_amdgcn_mfma_f32_16x16x32_bf16(
              af[mi], bf[nt], acc[mi][nt], 0, 0, 0);
#pragma unroll
      for (int mi = 2; mi < 4; ++mi)
#pragma unroll
        for (int nt = 2; nt < 4; ++nt)
          acc[mi][nt] = __builtin_amdgcn_mfma_f32_16x16x32_bf16(
              af[mi], bf[nt], acc[mi][nt], 0, 0, 0);
      __builtin_amdgcn_s_setprio(0);

      BAR();   // hazard (a): all waves' reads of this buffer retired

      if (nl) {
        stage_tile128(Abase + kof_n, Bbase + kof_n, cA, cB, w, lane);
        asm volatile("s_waitcnt vmcnt(4)" ::: "memory");  // tile t+1 landed
      } else {
        asm volatile("s_waitcnt vmcnt(0)" ::: "memory");  // drain final tiles
      }

      // ---- q4 (m-hi x n-lo): pure reg ops, overlaps staging issue ----
      __builtin_amdgcn_s_setprio(1);
#pragma unroll
      for (int mi = 2; mi < 4; ++mi)
#pragma unroll
        for (int nt = 0; nt < 2; ++nt)
          acc[mi][nt] = __builtin_amdgcn_mfma_f32_16x16x32_bf16(
              af[mi], bf[nt], acc[mi][nt], 0, 0, 0);
      __builtin_amdgcn_s_setprio(0);

      BAR();   // hazard (b): ALL waves' t+1 loads landed
    }
  }
}

// ---------------------------------------------------------------------------
// Fused QKV projection, 128^2 tiles, 256 threads. grid = (1536):
// [0,512) Q, [512,1024) K, [1024,1536) V^T (operands swapped:
// C[e][s] = sum_d Wv[e][d] x[s][d] -> (b,h,d,s) store contiguous in s).
// ---------------------------------------------------------------------------
__global__ __launch_bounds__(256, 4)
void qkv128_kernel(const u16* __restrict__ xb, const u16* __restrict__ wb,
                   const float* __restrict__ bq, const float* __restrict__ bk,
                   const float* __restrict__ bv,
                   u16* __restrict__ Qo, u16* __restrict__ Ko, u16* __restrict__ Vto)
{
  const int bx = blockIdx.x;
  const int wg = (bx & 7) * 192 + (bx >> 3);     // bijective XCD swizzle (1536%8==0)
  const int mat = wg >> 9;
  const int r   = wg & 511;

  int m0, n0;
  const u16 *A, *Bm;
  if (mat < 2) { m0 = (r >> 3) * 128; n0 = (r & 7) * 128; A = xb; Bm = wb + (size_t)mat * DM * DM; }
  else         { m0 = (r & 7) * 128;  n0 = (r >> 3) * 128; A = wb + (size_t)2 * DM * DM; Bm = xb; }

  floatx4 acc[4][4];
  gemm128_core(A, Bm, m0, n0, acc);

  const int tid = threadIdx.x;
  const int w = tid >> 6, lane = tid & 63;
  const int wm = w >> 1, wn = w & 1;
  const int quad = lane >> 4, l16 = lane & 15;

  if (mat < 2) {
    u16* dst = (mat == 0) ? Qo : Ko;
    const float* bias = (mat == 0) ? bq : bk;
#pragma unroll
    for (int ni = 0; ni < 4; ++ni) {
      const int n = n0 + wn * 64 + ni * 16 + l16;
      const float bb = bias[n];
      const int h = n >> 6, d = n & 63;
#pragma unroll
      for (int mi = 0; mi < 4; ++mi)
#pragma unroll
        for (int rr = 0; rr < 4; ++rr) {
          const int m = m0 + wm * 64 + mi * 16 + quad * 4 + rr;
          const int b = m >> 11, s = m & 2047;
          dst[((size_t)(b * NH + h) * SEQ + s) * DK + d] = f2bf(acc[mi][ni][rr] + bb);
        }
    }
  } else {
#pragma unroll
    for (int mi = 0; mi < 4; ++mi)
#pragma unroll
      for (int rr = 0; rr < 4; ++rr) {
        const int m = m0 + wm * 64 + mi * 16 + quad * 4 + rr;    // e in [0,1024)
        const float bb = bv[m];
        const int h = m >> 6, d = m & 63;
#pragma unroll
        for (int ni = 0; ni < 4; ++ni) {
          const int n = n0 + wn * 64 + ni * 16 + l16;            // (b,s) in [0,8192)
          const int b = n >> 11, s = n & 2047;
          Vto[((size_t)(b * NH + h) * DK + d) * SEQ + s] = f2bf(acc[mi][ni][rr] + bb);
        }
      }
  }
}

// ---------------------------------------------------------------------------
// Flash attention, causal, exp2-domain, no-rescale online softmax.
// grid = (64 bh, 16 qt-reversed). Block = 128 q-rows, 4 waves x 32 rows.
// Swapped QK^T (lane-local P) + cvt_pk + b64 P-stores (round 4, passed).
//
// Double-buffered K/V staging with counted vmcnt (transplant of the GEMM
// core's verified 2-barrier ledger).  Per tile kt (buf c = kt&1):
//   stage(kt+1 -> buf c^1)  [4 loads/wave]     (skip on last iter)
//   vmcnt(4)  [retires exactly tile kt's 4 loads -> kt landed]
//   BAR       [every wave's kt loads landed]
//   compute from buf c  (ds_reads + MFMA + softmax)
//   BAR       [all reads of buf c retired -> iter kt+1 may restage it]
// Ledger: buf c^1's last reader was iter kt-1's compute, sealed by that
// iter's closing BAR -> staging it at iter kt is safe.
// LDS 25.6 -> 41.9 KiB; __launch_bounds__(256,3) -> 3 blocks/CU (125.9 KiB).
// ---------------------------------------------------------------------------
#define AT_STR 72
__global__ __launch_bounds__(256, 3)
void attn_kernel(const u16* __restrict__ Q, const u16* __restrict__ Kx,
                 const u16* __restrict__ Vt, u16* __restrict__ O)
{
  __shared__ short Ks[2][64 * 64];
  __shared__ short Vs[2][64 * 64];
  __shared__ __align__(16) short Ps[4 * 16 * AT_STR];   // 16 rows per wave

  const int bh  = blockIdx.x;
  const int qtb = 15 - (int)blockIdx.y;
  const int q0  = qtb * 128;
  const int tid = threadIdx.x;
  const int w = tid >> 6, lane = tid & 63;
  const int quad = lane >> 4, l16 = lane & 15;
  const int r8 = lane >> 3, c8 = lane & 7;

  const u16* Qh = Q  + (size_t)bh * SEQ * DK;
  const u16* Kh = Kx + (size_t)bh * SEQ * DK;
  const u16* Vh = Vt + (size_t)bh * DK * SEQ;

  short8 qf[2][2];
#pragma unroll
  for (int qp = 0; qp < 2; ++qp) {
    const int qrow = q0 + w * 32 + qp * 16 + l16;
#pragma unroll
    for (int h = 0; h < 2; ++h)
      qf[qp][h] = *(const short8*)(Qh + (size_t)qrow * DK + h * 32 + quad * 8);
  }

  short8 vone;
#pragma unroll
  for (int j = 0; j < 8; ++j) vone[j] = (l16 == 0) ? (short)0x3F80 : (short)0;

  floatx4 o[2][4], ls[2];
#pragma unroll
  for (int qp = 0; qp < 2; ++qp) {
    ls[qp] = floatx4{0.f, 0.f, 0.f, 0.f};
#pragma unroll
    for (int dt = 0; dt < 4; ++dt) o[qp][dt] = floatx4{0.f, 0.f, 0.f, 0.f};
  }

  const float SC2 = 0.18033688011f;   // (1/8) * log2(e)
  const int ktmax = 2 * qtb + 2;
  short* Pw = Ps + w * 16 * AT_STR;   // this wave's 16-row P buffer
  const int sw = (c8 ^ r8) * 8;       // staging source swizzle (16B units)

  // ---- prologue: stage tile 0 into buf 0 (4 loads/wave) ----
#pragma unroll
  for (int c = 0; c < 2; ++c) {
    const int row8 = w * 16 + c * 8;   // wave-uniform
    async_copy16(Kh + (size_t)(row8 + r8) * DK + sw, Ks[0] + row8 * 64);
    async_copy16(Vh + (size_t)(row8 + r8) * SEQ + sw, Vs[0] + row8 * 64);
  }

  for (int kt = 0; kt < ktmax; ++kt) {
    const int cb = kt & 1;
    if (kt + 1 < ktmax) {
      const int k1 = (kt + 1) * 64;
#pragma unroll
      for (int c = 0; c < 2; ++c) {
        const int row8 = w * 16 + c * 8;   // wave-uniform
        async_copy16(Kh + (size_t)(k1 + row8 + r8) * DK + sw, Ks[cb ^ 1] + row8 * 64);
        async_copy16(Vh + (size_t)(row8 + r8) * SEQ + k1 + sw, Vs[cb ^ 1] + row8 * 64);
      }
      asm volatile("s_waitcnt vmcnt(4)" ::: "memory");  // tile kt landed (mine)
    } else {
      asm volatile("s_waitcnt vmcnt(0)" ::: "memory");  // drain final tile
    }
    BAR();   // every wave's tile-kt loads landed

    const int k0 = kt * 64;
    short8 kf[4][2], vf[4][2];
#pragma unroll
    for (int nt = 0; nt < 4; ++nt)
#pragma unroll
      for (int h = 0; h < 2; ++h) {
        kf[nt][h] = *(const short8*)(Ks[cb] + (nt * 16 + l16) * 64 + (((h * 4 + quad) ^ (l16 & 7)) * 8));
        vf[nt][h] = *(const short8*)(Vs[cb] + (nt * 16 + l16) * 64 + (((h * 4 + quad) ^ (l16 & 7)) * 8));
      }

#pragma unroll
    for (int qp = 0; qp < 2; ++qp) {
      const int frag0 = q0 + w * 32 + qp * 16;
      if (k0 <= frag0 + 15) {
        // swapped QK^T: D[key][query] -> lane holds q-row = l16,
        // keys k0 + nt*16 + quad*4 + r  (r = reg)
        floatx4 sc[4];
#pragma unroll
        for (int nt = 0; nt < 4; ++nt) {
          floatx4 z = floatx4{0.f, 0.f, 0.f, 0.f};
          z = __builtin_amdgcn_mfma_f32_16x16x32_bf16(kf[nt][0], qf[qp][0], z, 0, 0, 0);
          z = __builtin_amdgcn_mfma_f32_16x16x32_bf16(kf[nt][1], qf[qp][1], z, 0, 0, 0);
          sc[nt] = z;
        }
        const bool diag = (k0 + 63 > frag0);
        const int qrow = frag0 + l16;
#pragma unroll
        for (int nt = 0; nt < 4; ++nt)
#pragma unroll
          for (int r = 0; r < 4; ++r) {
            float s = sc[nt][r] * SC2;
            if (diag) {
              const int col = k0 + nt * 16 + quad * 4 + r;
              if (col > qrow) s = -1e30f;
            }
            sc[nt][r] = __builtin_amdgcn_exp2f(s);
          }
        // pack pairs + b64 stores: row = l16 (own q-row), cols nt*16+quad*4..+3
#pragma unroll
        for (int nt = 0; nt < 4; ++nt) {
          uint2v wv2;
          wv2[0] = cvt_pk_bf16(sc[nt][0], sc[nt][1]);
          wv2[1] = cvt_pk_bf16(sc[nt][2], sc[nt][3]);
          *(short4v*)(Pw + l16 * AT_STR + nt * 16 + quad * 4) =
              __builtin_bit_cast(short4v, wv2);
        }
        asm volatile("" ::: "memory");   // keep pf reads after P writes
        short8 pf[2];
#pragma unroll
        for (int h = 0; h < 2; ++h)
          pf[h] = *(const short8*)(Pw + l16 * AT_STR + h * 32 + quad * 8);
#pragma unroll
        for (int dt = 0; dt < 4; ++dt) {
          o[qp][dt] = __builtin_amdgcn_mfma_f32_16x16x32_bf16(pf[0], vf[dt][0], o[qp][dt], 0, 0, 0);
          o[qp][dt] = __builtin_amdgcn_mfma_f32_16x16x32_bf16(pf[1], vf[dt][1], o[qp][dt], 0, 0, 0);
        }
        ls[qp] = __builtin_amdgcn_mfma_f32_16x16x32_bf16(pf[0], vone, ls[qp], 0, 0, 0);
        ls[qp] = __builtin_amdgcn_mfma_f32_16x16x32_bf16(pf[1], vone, ls[qp], 0, 0, 0);
      }
    }

    BAR();   // all reads of buf cb retired -> next iter may restage it
  }

  const int b = bh >> 4, h = bh & 15;
#pragma unroll
  for (int qp = 0; qp < 2; ++qp) {
    const int frag0 = q0 + w * 32 + qp * 16;
#pragma unroll
    for (int r = 0; r < 4; ++r) {
      const float lv  = __shfl(ls[qp][r], lane & 48);
      const float inv = 1.0f / fmaxf(lv, 1e-20f);
      const int row   = frag0 + quad * 4 + r;
      const size_t base = ((size_t)b * SEQ + row) * DM + h * DK;
#pragma unroll
      for (int dt = 0; dt < 4; ++dt)
        O[base + dt * 16 + l16] = f2bf(o[qp][dt][r] * inv);
    }
  }
}

// ---------------------------------------------------------------------------
// Output projection: out = O'(bf16) @ Wo_b^T + bo, fp32 out.
// 128^2 tiles, grid = 512 -> 2 balanced rounds at 4 blocks/CU.
// ---------------------------------------------------------------------------
__global__ __launch_bounds__(256, 4)
void oproj128_kernel(const u16* __restrict__ A, const u16* __restrict__ Wob,
                     const float* __restrict__ bo, float* __restrict__ out)
{
  const int bx = blockIdx.x;
  const int wg = (bx & 7) * 64 + (bx >> 3);      // 512 % 8 == 0
  const int m0 = (wg >> 3) * 128, n0 = (wg & 7) * 128;

  floatx4 acc[4][4];
  gemm128_core(A, Wob, m0, n0, acc);

  const int tid = threadIdx.x;
  const int w = tid >> 6, lane = tid & 63;
  const int wm = w >> 1, wn = w & 1;
  const int quad = lane >> 4, l16 = lane & 15;

#pragma unroll
  for (int ni = 0; ni < 4; ++ni) {
    const int n = n0 + wn * 64 + ni * 16 + l16;
    const float bb = bo[n];
#pragma unroll
    for (int mi = 0; mi < 4; ++mi)
#pragma unroll
      for (int rr = 0; rr < 4; ++rr) {
        const int m = m0 + wm * 64 + mi * 16 + quad * 4 + rr;
        out[(size_t)m * DM + n] = acc[mi][ni][rr] + bb;
      }
  }
}

extern "C" void kernel_launch(void* const* d_in, const int* in_sizes, int n_in,
                              void* d_out, int out_size, void* d_ws, size_t ws_size,
                              hipStream_t stream)
{
  const float* x  = (const float*)d_in[0];
  const float* Wq = (const float*)d_in[1];
  const float* bq = (const float*)d_in[2];
  const float* Wk = (const float*)d_in[3];
  const float* bk = (const float*)d_in[4];
  const float* Wv = (const float*)d_in[5];
  const float* bv = (const float*)d_in[6];
  const float* Wo = (const float*)d_in[7];
  const float* bo = (const float*)d_in[8];
  float* out = (float*)d_out;

  // ws (64 MiB): Q, K, Vt, O'  (qws doubles as Wo_b after attn)
  u16* qws  = (u16*)d_ws;                       // (b,h,s,d)  bf16, 16 MiB
  u16* kws  = qws  + (size_t)M_ROWS * DM;       // (b,h,s,d)  bf16, 16 MiB
  u16* vtws = kws  + (size_t)M_ROWS * DM;       // (b,h,d,s)  bf16, 16 MiB
  u16* ows  = vtws + (size_t)M_ROWS * DM;       // O' (b,s,h*d) bf16, 16 MiB

  // d_out doubles as scratch until oproj overwrites all of it:
  //   [0, 16 MiB)  : x bf16
  //   [16, 22 MiB) : Wq/Wk/Wv bf16 packed [3][DM][DM]
  u16* xb = (u16*)d_out;
  u16* wb = xb + (size_t)M_ROWS * DM;
  u16* wo_b = qws;                              // qws dead after attn

  cvt4_kernel  <<<dim3(1024, 4), 256, 0, stream>>>(x, Wq, Wk, Wv, xb, wb);
  qkv128_kernel<<<dim3(1536), 256, 0, stream>>>(xb, wb, bq, bk, bv, qws, kws, vtws);
  attn_kernel  <<<dim3(64, 16), 256, 0, stream>>>(qws, kws, vtws, ows);
  cvt1_kernel  <<<dim3(1024), 256, 0, stream>>>(Wo, wo_b, (DM * DM) / 4);
  oproj128_kernel<<<dim3(512), 256, 0, stream>>>(ows, wo_b, bo, out);
}